// Round 9
// baseline (1209.540 us; speedup 1.0000x reference)
//
#include <hip/hip_runtime.h>
#include <hip/hip_bf16.h>

#define NN 50000
#define NE 800000
#define CIN 256
#define HH 64
#define NBKT 391          // ceil(NN/128): dst>>7 buckets of 128 nodes
#define B1 256            // pass-A blocks
#define EPB 3125          // edges per pass-A block (B1*EPB == NE)
#define NGB 782           // ceil(NN/64) GEMM blocks (64 rows each)

typedef __attribute__((ext_vector_type(8))) short short8;
typedef __attribute__((ext_vector_type(4))) float f32x4;

__device__ __forceinline__ float bf2f(ushort u) {
    union { unsigned int i; float f; } v; v.i = ((unsigned int)u) << 16; return v.f;
}
__device__ __forceinline__ ushort f2bf(float f) {
    __hip_bfloat16 b = __float2bfloat16(f);   // RNE
    return *reinterpret_cast<ushort*>(&b);
}

// ---------------- prep: all weights -> bf16 MFMA B-frag layout ---------------
__global__ __launch_bounds__(256) void k_prep(
    const float* __restrict__ W_in, const float* __restrict__ LW,
    const float* __restrict__ W_out, ushort* __restrict__ Wp)
{
    const int tid = blockIdx.x * 256 + threadIdx.x;   // 32768 total
    if (tid < 16384) {
        const int i = tid & 7;
        const int l = (tid >> 3) & 63;
        const int s = (tid >> 9) & 7;
        const int t = tid >> 12;
        const int k = s * 32 + (l >> 4) * 8 + i;
        const int c = t * 16 + (l & 15);
        Wp[tid] = f2bf(W_in[k * HH + c]);
    } else {
        const int q = (tid - 16384) & 4095;
        const int m = (tid - 16384) >> 12;            // 0..3
        const int i = q & 7;
        const int l = (q >> 3) & 63;
        const int s = (q >> 9) & 1;
        const int t = q >> 10;
        const int k = s * 32 + (l >> 4) * 8 + i;
        const int c = t * 16 + (l & 15);
        const float* Wm = (m < 3) ? (LW + m * HH * HH) : W_out;
        Wp[tid] = f2bf(Wm[k * HH + c]);
    }
}

// ------- fused: pass-A LDS histogram (blocks < B1) | MFMA in-linear ----------
__global__ __launch_bounds__(256) void k_fused(
    const float* __restrict__ x, const ushort* __restrict__ Wp,
    const float* __restrict__ b, const int* __restrict__ dst,
    int* __restrict__ H, ushort* __restrict__ h_bf)
{
    __shared__ int hist[NBKT];
    if (blockIdx.x < B1) {
        for (int t = threadIdx.x; t < NBKT; t += 256) hist[t] = 0;
        __syncthreads();
        const int e0 = blockIdx.x * EPB;
        for (int i = threadIdx.x; i < EPB; i += 256)
            atomicAdd(&hist[dst[e0 + i] >> 7], 1);
        __syncthreads();
        for (int t = threadIdx.x; t < NBKT; t += 256)
            H[t * B1 + blockIdx.x] = hist[t];
        return;
    }
    const int w = threadIdx.x >> 6;          // wave 0..3
    const int l = threadIdx.x & 63;
    const int R0 = (blockIdx.x - B1) * 64 + w * 16;
    const int arow = R0 + (l & 15);
    const int xrow = (arow < NN) ? arow : (NN - 1);
    const float* xr = x + (size_t)xrow * CIN + (l >> 4) * 8;
    const short8* WpV = (const short8*)Wp;

    f32x4 acc0 = {0,0,0,0}, acc1 = {0,0,0,0}, acc2 = {0,0,0,0}, acc3 = {0,0,0,0};
    #pragma unroll
    for (int s = 0; s < 8; ++s) {
        const float4 xa = *(const float4*)(xr + s * 32);
        const float4 xb = *(const float4*)(xr + s * 32 + 4);
        short8 af;
        af[0] = (short)f2bf(xa.x); af[1] = (short)f2bf(xa.y);
        af[2] = (short)f2bf(xa.z); af[3] = (short)f2bf(xa.w);
        af[4] = (short)f2bf(xb.x); af[5] = (short)f2bf(xb.y);
        af[6] = (short)f2bf(xb.z); af[7] = (short)f2bf(xb.w);
        acc0 = __builtin_amdgcn_mfma_f32_16x16x32_bf16(af, WpV[(0*8+s)*64 + l], acc0, 0, 0, 0);
        acc1 = __builtin_amdgcn_mfma_f32_16x16x32_bf16(af, WpV[(1*8+s)*64 + l], acc1, 0, 0, 0);
        acc2 = __builtin_amdgcn_mfma_f32_16x16x32_bf16(af, WpV[(2*8+s)*64 + l], acc2, 0, 0, 0);
        acc3 = __builtin_amdgcn_mfma_f32_16x16x32_bf16(af, WpV[(3*8+s)*64 + l], acc3, 0, 0, 0);
    }
    const int colb = l & 15;
    const int rbase = R0 + (l >> 4) * 4;
    #pragma unroll
    for (int t = 0; t < 4; ++t) {
        const f32x4 a = (t == 0) ? acc0 : (t == 1) ? acc1 : (t == 2) ? acc2 : acc3;
        const float bb = b[t * 16 + colb];
        #pragma unroll
        for (int r = 0; r < 4; ++r) {
            const int row = rbase + r;
            if (row < NN)
                h_bf[(size_t)row * HH + t * 16 + colb] = f2bf(a[r] + bb);
        }
    }
}

// ------- scanH: bucket sums + exclusive scan; in-place (bkt,blk) offsets -----
__global__ __launch_bounds__(512) void k_scanH(
    int* __restrict__ H, int* __restrict__ Sx, int* __restrict__ bcnt)
{
    __shared__ int s[512];
    const int t = threadIdx.x;
    int rowsum = 0;
    if (t < NBKT) {
        const int4* row = (const int4*)(H + t * B1);
        #pragma unroll 8
        for (int c = 0; c < B1 / 4; ++c) {
            const int4 v = row[c];
            rowsum += v.x + v.y + v.z + v.w;
        }
    }
    s[t] = rowsum;
    __syncthreads();
    #pragma unroll
    for (int off = 1; off < 512; off <<= 1) {
        const int add = (t >= off) ? s[t - off] : 0;
        __syncthreads();
        s[t] += add;
        __syncthreads();
    }
    if (t < NBKT) {
        const int rowstart = s[t] - rowsum;
        Sx[t] = rowstart;
        bcnt[t] = rowsum;
        int run = rowstart;
        int4* row = (int4*)(H + t * B1);
        for (int c = 0; c < B1 / 4; ++c) {
            int4 v = row[c];
            int4 o;
            o.x = run; run += v.x;
            o.y = run; run += v.y;
            o.z = run; run += v.z;
            o.w = run; run += v.w;
            row[c] = o;
        }
    }
}

// ------- scatterA: bucket-group edges; pack (src | dlow<<16, w) --------------
// Within-bucket order is irrelevant (LDS-atomic aggregation is order-free).
__global__ __launch_bounds__(256) void k_scatterA(
    const int* __restrict__ src, const int* __restrict__ dst,
    const float* __restrict__ ew, const int* __restrict__ H,
    int2* __restrict__ ebuck)
{
    __shared__ int cur[NBKT];
    for (int t = threadIdx.x; t < NBKT; t += 256)
        cur[t] = H[t * B1 + blockIdx.x];
    __syncthreads();
    const int e0 = blockIdx.x * EPB;
    for (int i = threadIdx.x; i < EPB; i += 256) {
        const int e = e0 + i;
        const int d = dst[e];
        const int pos = atomicAdd(&cur[d >> 7], 1);
        ebuck[pos] = make_int2(src[e] | ((d & 127) << 16), __float_as_int(ew[e]));
    }
}

// ---------------- fused layer: block = one 128-node bucket, 8 waves ----------
// Phase 1: waves stream disjoint slices of the bucket's edge list; per edge,
// 64 lanes gather cur_in[src] (128B row) and LDS-atomicAdd into agg[dlow][j]
// (bank j%32, 2-way alias = free; ds_add f32 is fire-and-forget).
// Phase 2: wave w MFMAs its 16-node tile (all 64 cols, 8 MFMAs), bias via
// aggw (sum of edge weights), relu; FINAL recomputes hidden + @W_out.
template<bool FINAL>
__global__ __launch_bounds__(512) void k_layer(
    const ushort* __restrict__ cur_in, ushort* __restrict__ cur_out,
    const int2* __restrict__ ebuck, const int* __restrict__ Sx,
    const int* __restrict__ bcnt,
    const ushort* __restrict__ WpL, const float* __restrict__ bvec,
    const float* __restrict__ temp,
    const ushort* __restrict__ hbf, const ushort* __restrict__ c1,
    const ushort* __restrict__ WpO, const float* __restrict__ bout,
    float* __restrict__ outp)
{
    __shared__ float agg[128][HH];     // 32 KB; atomic target
    __shared__ float aggw[128];        // per-node sum of edge weights
    __shared__ int2  es[8][64];        // per-wave edge-metadata staging
    __shared__ ushort ts[8][16][72];   // per-wave bf16 A-tiles (padded rows)
    const int wv = threadIdx.x >> 6;
    const int j  = threadIdx.x & 63;
    const int bkt = blockIdx.x;
    const int base = Sx[bkt];
    const int cntE = bcnt[bkt];

    for (int i = threadIdx.x; i < 128 * HH; i += 512) (&agg[0][0])[i] = 0.0f;
    if (threadIdx.x < 128) aggw[threadIdx.x] = 0.0f;
    __syncthreads();

    // ---- phase 1: edge streaming ----
    const int per = (cntE + 7) >> 3;
    const int s0 = min(wv * per, cntE);
    const int s1 = min(s0 + per, cntE);
    for (int bb = s0; bb < s1; bb += 64) {
        const int m = min(64, s1 - bb);
        if (j < m) es[wv][j] = ebuck[base + bb + j];
        for (int g = 0; g < m; g += 16) {
            float vv[16], ww[16];
            int   dl[16];
            #pragma unroll
            for (int u = 0; u < 16; ++u) {
                const int idx = g + u;
                const int sel = (idx < m) ? idx : 0;   // clamp: dup line, cheap
                const int2 p = es[wv][sel];            // LDS broadcast read
                const int srcn = p.x & 0xFFFF;
                dl[u] = (p.x >> 16) & 127;
                ww[u] = (idx < m) ? __int_as_float(p.y) : 0.0f;
                vv[u] = bf2f(cur_in[(size_t)srcn * HH + j]);
            }
            #pragma unroll
            for (int u = 0; u < 16; ++u)
                atomicAdd(&agg[dl[u]][j], ww[u] * vv[u]);
            if (j == 0) {
                #pragma unroll
                for (int u = 0; u < 16; ++u) atomicAdd(&aggw[dl[u]], ww[u]);
            }
        }
    }
    __syncthreads();

    // ---- phase 2: per-wave 16-node tile, MFMA 64x64 linear ----
    const int n0 = bkt * 128 + wv * 16;
    #pragma unroll
    for (int r = 0; r < 16; ++r)
        ts[wv][r][j] = f2bf(agg[wv * 16 + r][j]);      // row copy: conflict-free
    const int lr = j & 15;
    const int lg = j >> 4;
    const short8 a0 = *(const short8*)&ts[wv][lr][lg * 8];
    const short8 a1 = *(const short8*)&ts[wv][lr][32 + lg * 8];
    const short8* WpV = (const short8*)WpL;
    f32x4 z0 = {0,0,0,0}, z1 = {0,0,0,0}, z2 = {0,0,0,0}, z3 = {0,0,0,0};
    z0 = __builtin_amdgcn_mfma_f32_16x16x32_bf16(a0, WpV[0*64 + j], z0, 0, 0, 0);
    z0 = __builtin_amdgcn_mfma_f32_16x16x32_bf16(a1, WpV[1*64 + j], z0, 0, 0, 0);
    z1 = __builtin_amdgcn_mfma_f32_16x16x32_bf16(a0, WpV[2*64 + j], z1, 0, 0, 0);
    z1 = __builtin_amdgcn_mfma_f32_16x16x32_bf16(a1, WpV[3*64 + j], z1, 0, 0, 0);
    z2 = __builtin_amdgcn_mfma_f32_16x16x32_bf16(a0, WpV[4*64 + j], z2, 0, 0, 0);
    z2 = __builtin_amdgcn_mfma_f32_16x16x32_bf16(a1, WpV[5*64 + j], z2, 0, 0, 0);
    z3 = __builtin_amdgcn_mfma_f32_16x16x32_bf16(a0, WpV[6*64 + j], z3, 0, 0, 0);
    z3 = __builtin_amdgcn_mfma_f32_16x16x32_bf16(a1, WpV[7*64 + j], z3, 0, 0, 0);

    float swr[4];
    #pragma unroll
    for (int r = 0; r < 4; ++r) swr[r] = aggw[wv * 16 + lg * 4 + r];
    float t0v = 0, t1v = 0, t2v = 0, t3v = 0;
    if (FINAL) { t0v = temp[0]; t1v = temp[1]; t2v = temp[2]; t3v = temp[3]; }
    #pragma unroll
    for (int t = 0; t < 4; ++t) {
        const f32x4 zt = (t == 0) ? z0 : (t == 1) ? z1 : (t == 2) ? z2 : z3;
        const float bb = bvec[t * 16 + lr];
        #pragma unroll
        for (int r = 0; r < 4; ++r) {
            const int node = n0 + lg * 4 + r;
            if (node < NN) {
                const float z  = zt[r] + swr[r] * bb;
                const float rv = fmaxf(z, 0.0f);
                const size_t o = (size_t)node * HH + t * 16 + lr;
                if (!FINAL) {
                    cur_out[o] = f2bf(rv);
                } else {
                    const float hid = t0v * bf2f(hbf[o]) + t1v * bf2f(c1[o])
                                    + t2v * bf2f(cur_in[o]) + t3v * rv;
                    ts[wv][lg * 4 + r][t * 16 + lr] = f2bf(hid);
                }
            }
        }
    }
    if (FINAL) {
        // wave-private ts; lockstep + waitcnt order write->read, no barrier
        const short8 b0 = *(const short8*)&ts[wv][lr][lg * 8];
        const short8 b1 = *(const short8*)&ts[wv][lr][32 + lg * 8];
        const short8* WoV = (const short8*)WpO;
        f32x4 o0 = {0,0,0,0}, o1 = {0,0,0,0}, o2 = {0,0,0,0}, o3 = {0,0,0,0};
        o0 = __builtin_amdgcn_mfma_f32_16x16x32_bf16(b0, WoV[0*64 + j], o0, 0, 0, 0);
        o0 = __builtin_amdgcn_mfma_f32_16x16x32_bf16(b1, WoV[1*64 + j], o0, 0, 0, 0);
        o1 = __builtin_amdgcn_mfma_f32_16x16x32_bf16(b0, WoV[2*64 + j], o1, 0, 0, 0);
        o1 = __builtin_amdgcn_mfma_f32_16x16x32_bf16(b1, WoV[3*64 + j], o1, 0, 0, 0);
        o2 = __builtin_amdgcn_mfma_f32_16x16x32_bf16(b0, WoV[4*64 + j], o2, 0, 0, 0);
        o2 = __builtin_amdgcn_mfma_f32_16x16x32_bf16(b1, WoV[5*64 + j], o2, 0, 0, 0);
        o3 = __builtin_amdgcn_mfma_f32_16x16x32_bf16(b0, WoV[6*64 + j], o3, 0, 0, 0);
        o3 = __builtin_amdgcn_mfma_f32_16x16x32_bf16(b1, WoV[7*64 + j], o3, 0, 0, 0);
        #pragma unroll
        for (int t = 0; t < 4; ++t) {
            const f32x4 ot = (t == 0) ? o0 : (t == 1) ? o1 : (t == 2) ? o2 : o3;
            const float bo = bout[t * 16 + lr];
            #pragma unroll
            for (int r = 0; r < 4; ++r) {
                const int node = n0 + lg * 4 + r;
                if (node < NN)
                    outp[(size_t)node * HH + t * 16 + lr] = ot[r] + bo;
            }
        }
    }
}

extern "C" void kernel_launch(void* const* d_in, const int* in_sizes, int n_in,
                              void* d_out, int out_size, void* d_ws, size_t ws_size,
                              hipStream_t stream)
{
    const float* x     = (const float*)d_in[0];
    const int*   ei    = (const int*)d_in[1];
    const float* ew    = (const float*)d_in[2];
    const float* W_in  = (const float*)d_in[3];
    const float* b_in  = (const float*)d_in[4];
    const float* LW    = (const float*)d_in[5];
    const float* Lb    = (const float*)d_in[6];
    const float* W_out = (const float*)d_in[7];
    const float* b_out = (const float*)d_in[8];
    const float* b_tmp = (const float*)d_in[9];
    const int* src = ei;
    const int* dst = ei + NE;

    char* p = (char*)d_ws;
    ushort* h_bf  = (ushort*)p;  p += (size_t)NN * HH * 2;        // 6.4 MB
    ushort* curA  = (ushort*)p;  p += (size_t)NN * HH * 2;
    ushort* curB  = (ushort*)p;  p += (size_t)NN * HH * 2;
    int2*   ebuck = (int2*)p;    p += (size_t)NE * 8;             // 6.4 MB
    int*    H     = (int*)p;     p += (size_t)NBKT * B1 * 4;      // 400 KB
    int*    Sx    = (int*)p;     p += (NBKT + 1) * 4;
    int*    bcnt  = (int*)p;     p += (NBKT + 1) * 4;
    ushort* Wp    = (ushort*)p;  p += 32768 * 2;                  // 64 KB
    float*  out   = (float*)d_out;

    const ushort* WpIn  = Wp;
    const ushort* WpL0  = Wp + 16384;
    const ushort* WpL1  = Wp + 16384 + 4096;
    const ushort* WpL2  = Wp + 16384 + 2 * 4096;
    const ushort* WpOut = Wp + 16384 + 3 * 4096;

    // weights -> bf16 MFMA fragments
    k_prep<<<128, 256, 0, stream>>>(W_in, LW, W_out, Wp);
    // pass-A histogram (LDS only) fused with MFMA in-linear
    k_fused<<<B1 + NGB, 256, 0, stream>>>(x, WpIn, b_in, dst, H, h_bf);
    // bucket bases + per-(bucket,block) offsets
    k_scanH<<<1, 512, 0, stream>>>(H, Sx, bcnt);
    // bucket-grouped edge list (order within bucket irrelevant)
    k_scatterA<<<B1, 256, 0, stream>>>(src, dst, ew, H, ebuck);

    // 3 fused propagation layers; FINAL recomputes hidden from bf16 terms
    k_layer<false><<<NBKT, 512, 0, stream>>>(h_bf, curA, ebuck, Sx, bcnt,
                                             WpL0, Lb + 0 * HH, b_tmp,
                                             nullptr, nullptr, nullptr, nullptr, nullptr);
    k_layer<false><<<NBKT, 512, 0, stream>>>(curA, curB, ebuck, Sx, bcnt,
                                             WpL1, Lb + 1 * HH, b_tmp,
                                             nullptr, nullptr, nullptr, nullptr, nullptr);
    k_layer<true><<<NBKT, 512, 0, stream>>>(curB, nullptr, ebuck, Sx, bcnt,
                                            WpL2, Lb + 2 * HH, b_tmp,
                                            h_bf, curA, WpOut, b_out, out);
}

// Round 10
// 158.960 us; speedup vs baseline: 7.6091x; 7.6091x over previous
//
#include <hip/hip_runtime.h>
#include <hip/hip_bf16.h>

#define NN 50000
#define NE 800000
#define CIN 256
#define HH 64
#define NBINS 196         // dst>>8 buckets (50000/256)
#define B1 256            // pass-A blocks
#define EPB 3125          // edges per pass-A block (B1*EPB == NE)
#define NGB 782           // ceil(NN/64) GEMM blocks (64 rows each)
#define NLB 3125          // NN/16 layer blocks (16 nodes each)

typedef unsigned long long u64;
typedef __attribute__((ext_vector_type(8))) short short8;
typedef __attribute__((ext_vector_type(4))) float f32x4;

__device__ __forceinline__ float bf2f(ushort u) {
    union { unsigned int i; float f; } v; v.i = ((unsigned int)u) << 16; return v.f;
}
__device__ __forceinline__ ushort f2bf(float f) {
    __hip_bfloat16 b = __float2bfloat16(f);   // RNE
    return *reinterpret_cast<ushort*>(&b);
}

// ---------------- prep: all weights -> bf16 MFMA B-frag layout ---------------
__global__ __launch_bounds__(256) void k_prep(
    const float* __restrict__ W_in, const float* __restrict__ LW,
    const float* __restrict__ W_out, ushort* __restrict__ Wp)
{
    const int tid = blockIdx.x * 256 + threadIdx.x;   // 32768 total
    if (tid < 16384) {
        const int i = tid & 7;
        const int l = (tid >> 3) & 63;
        const int s = (tid >> 9) & 7;
        const int t = tid >> 12;
        const int k = s * 32 + (l >> 4) * 8 + i;
        const int c = t * 16 + (l & 15);
        Wp[tid] = f2bf(W_in[k * HH + c]);
    } else {
        const int q = (tid - 16384) & 4095;
        const int m = (tid - 16384) >> 12;            // 0..3
        const int i = q & 7;
        const int l = (q >> 3) & 63;
        const int s = (q >> 9) & 1;
        const int t = q >> 10;
        const int k = s * 32 + (l >> 4) * 8 + i;
        const int c = t * 16 + (l & 15);
        const float* Wm = (m < 3) ? (LW + m * HH * HH) : W_out;
        Wp[tid] = f2bf(Wm[k * HH + c]);
    }
}

// ------- fused: pass-A LDS histogram (blocks < B1) | MFMA in-linear ----------
__global__ __launch_bounds__(256) void k_fused(
    const float* __restrict__ x, const ushort* __restrict__ Wp,
    const float* __restrict__ b, const int* __restrict__ dst,
    int* __restrict__ H, ushort* __restrict__ h_bf)
{
    __shared__ int hist[NBINS];
    if (blockIdx.x < B1) {
        for (int t = threadIdx.x; t < NBINS; t += 256) hist[t] = 0;
        __syncthreads();
        const int e0 = blockIdx.x * EPB;
        for (int i = threadIdx.x; i < EPB; i += 256)
            atomicAdd(&hist[dst[e0 + i] >> 8], 1);
        __syncthreads();
        for (int t = threadIdx.x; t < NBINS; t += 256)
            H[t * B1 + blockIdx.x] = hist[t];
        return;
    }
    const int w = threadIdx.x >> 6;          // wave 0..3
    const int l = threadIdx.x & 63;
    const int R0 = (blockIdx.x - B1) * 64 + w * 16;
    const int arow = R0 + (l & 15);
    const int xrow = (arow < NN) ? arow : (NN - 1);
    const float* xr = x + (size_t)xrow * CIN + (l >> 4) * 8;
    const short8* WpV = (const short8*)Wp;

    f32x4 acc0 = {0,0,0,0}, acc1 = {0,0,0,0}, acc2 = {0,0,0,0}, acc3 = {0,0,0,0};
    #pragma unroll
    for (int s = 0; s < 8; ++s) {
        const float4 xa = *(const float4*)(xr + s * 32);
        const float4 xb = *(const float4*)(xr + s * 32 + 4);
        short8 af;
        af[0] = (short)f2bf(xa.x); af[1] = (short)f2bf(xa.y);
        af[2] = (short)f2bf(xa.z); af[3] = (short)f2bf(xa.w);
        af[4] = (short)f2bf(xb.x); af[5] = (short)f2bf(xb.y);
        af[6] = (short)f2bf(xb.z); af[7] = (short)f2bf(xb.w);
        acc0 = __builtin_amdgcn_mfma_f32_16x16x32_bf16(af, WpV[(0*8+s)*64 + l], acc0, 0, 0, 0);
        acc1 = __builtin_amdgcn_mfma_f32_16x16x32_bf16(af, WpV[(1*8+s)*64 + l], acc1, 0, 0, 0);
        acc2 = __builtin_amdgcn_mfma_f32_16x16x32_bf16(af, WpV[(2*8+s)*64 + l], acc2, 0, 0, 0);
        acc3 = __builtin_amdgcn_mfma_f32_16x16x32_bf16(af, WpV[(3*8+s)*64 + l], acc3, 0, 0, 0);
    }
    const int colb = l & 15;
    const int rbase = R0 + (l >> 4) * 4;
    #pragma unroll
    for (int t = 0; t < 4; ++t) {
        const f32x4 a = (t == 0) ? acc0 : (t == 1) ? acc1 : (t == 2) ? acc2 : acc3;
        const float bb = b[t * 16 + colb];
        #pragma unroll
        for (int r = 0; r < 4; ++r) {
            const int row = rbase + r;
            if (row < NN)
                h_bf[(size_t)row * HH + t * 16 + colb] = f2bf(a[r] + bb);
        }
    }
}

// ------- scanH: in-place exclusive scan of H (bin-major), bucket bases -------
__global__ __launch_bounds__(256) void k_scanH(
    int* __restrict__ H, int* __restrict__ Sx, int* __restrict__ bcnt)
{
    __shared__ int s[256];
    const int t = threadIdx.x;
    int rowsum = 0;
    if (t < NBINS) {
        const int4* row = (const int4*)(H + t * B1);
        #pragma unroll 8
        for (int c = 0; c < B1 / 4; ++c) {
            const int4 v = row[c];
            rowsum += v.x + v.y + v.z + v.w;
        }
    }
    s[t] = (t < NBINS) ? rowsum : 0;
    __syncthreads();
    #pragma unroll
    for (int off = 1; off < 256; off <<= 1) {
        const int add = (t >= off) ? s[t - off] : 0;
        __syncthreads();
        s[t] += add;
        __syncthreads();
    }
    if (t < NBINS) {
        const int rowstart = s[t] - rowsum;
        Sx[t] = rowstart;
        bcnt[t] = rowsum;
        int run = rowstart;
        int4* row = (int4*)(H + t * B1);
        for (int c = 0; c < B1 / 4; ++c) {
            int4 v = row[c];
            int4 o;
            o.x = run; run += v.x;
            o.y = run; run += v.y;
            o.z = run; run += v.z;
            o.w = run; run += v.w;
            row[c] = o;
        }
    }
}

// ------- scatterA: place edges into dst-high buckets (LDS cursors only) ------
__global__ __launch_bounds__(256) void k_scatterA(
    const int* __restrict__ src, const int* __restrict__ dst,
    const float* __restrict__ ew, const int* __restrict__ H,
    int2* __restrict__ tmp_e, ushort* __restrict__ tmp_low)
{
    __shared__ int cur[NBINS];
    for (int t = threadIdx.x; t < NBINS; t += 256)
        cur[t] = H[t * B1 + blockIdx.x];
    __syncthreads();
    const int e0 = blockIdx.x * EPB;
    for (int i = threadIdx.x; i < EPB; i += 256) {
        const int e = e0 + i;
        const int d = dst[e];
        const int pos = atomicAdd(&cur[d >> 8], 1);
        tmp_e[pos] = make_int2(src[e], __float_as_int(ew[e]));
        tmp_low[pos] = (ushort)(d & 255);
    }
}

// ------- sortB: per high-bucket LSD pass -> epack, rowptr, cnt ---------------
__global__ __launch_bounds__(512) void k_sortB(
    const int2* __restrict__ tmp_e, const ushort* __restrict__ tmp_low,
    const int* __restrict__ Sx, const int* __restrict__ bcnt,
    int2* __restrict__ epack, int* __restrict__ rowptr, int* __restrict__ cnt)
{
    __shared__ int hist[256], s[256], curs[256];
    const int b = blockIdx.x;
    const int base = Sx[b];
    const int cntE = bcnt[b];
    const int t = threadIdx.x;
    if (t < 256) hist[t] = 0;
    __syncthreads();
    for (int i = t; i < cntE; i += 512)
        atomicAdd(&hist[tmp_low[base + i]], 1);
    __syncthreads();
    if (t < 256) s[t] = hist[t];
    __syncthreads();
    #pragma unroll
    for (int off = 1; off < 256; off <<= 1) {
        const int add = (t < 256 && t >= off) ? s[t - off] : 0;
        __syncthreads();
        if (t < 256) s[t] += add;
        __syncthreads();
    }
    if (t < 256) {
        const int excl = s[t] - hist[t];
        curs[t] = excl;
        const int d = b * 256 + t;
        if (d < NN) { rowptr[d] = base + excl; cnt[d] = hist[t]; }
    }
    __syncthreads();
    for (int i = t; i < cntE; i += 512) {
        const int2 e = tmp_e[base + i];
        const int low = (int)tmp_low[base + i];
        const int pos = base + atomicAdd(&curs[low], 1);
        epack[pos] = e;
    }
}

// ---------------- fused layer: block = 16 nodes, 4 waves ---------------------
template<bool FINAL>
__global__ __launch_bounds__(256) void k_layer(
    const ushort* __restrict__ cur_in, ushort* __restrict__ cur_out,
    const int2* __restrict__ epack, const int* __restrict__ rowptr,
    const int* __restrict__ cnt,
    const ushort* __restrict__ WpL, const float* __restrict__ bvec,
    const float* __restrict__ temp,
    const ushort* __restrict__ hbf, const ushort* __restrict__ c1,
    const ushort* __restrict__ WpO, const float* __restrict__ bout,
    float* __restrict__ outp)
{
    __shared__ int2  es[4][64];
    __shared__ ushort ts[16][72];      // padded: bank-even b128 reads
    __shared__ float swv[16];          // per-node sum of edge weights (bias term)
    const int w = threadIdx.x >> 6;
    const int j = threadIdx.x & 63;
    const int nb = blockIdx.x * 16;

    // ---- gather-aggregate: wave w handles nodes nb + w*4 + q ----
    #pragma unroll
    for (int q = 0; q < 4; ++q) {
        const int n  = nb + w * 4 + q;
        const int rs = rowptr[n];
        const int rc = cnt[n];
        float acc = 0.0f;
        float sw  = 0.0f;
        for (int base = 0; base < rc; base += 64) {
            const int m = min(rc - base, 64);
            if (j < m) es[w][j] = epack[rs + base + j];
            for (int g = 0; g < m; g += 8) {           // group 8: less round-up waste
                float vv[8], ww[8];
                #pragma unroll
                for (int u = 0; u < 8; ++u) {
                    const int idx = g + u;
                    const int sel = (idx < m) ? idx : 0;   // clamp: dup line, cheap
                    const int2 p = es[w][sel];             // LDS broadcast read
                    ww[u] = (idx < m) ? __int_as_float(p.y) : 0.0f;
                    vv[u] = bf2f(cur_in[(size_t)p.x * HH + j]);
                }
                #pragma unroll
                for (int u = 0; u < 8; ++u) { acc = fmaf(ww[u], vv[u], acc); sw += ww[u]; }
            }
        }
        ts[w * 4 + q][j] = f2bf(acc);
        if (j == 0) swv[w * 4 + q] = sw;
    }
    __syncthreads();

    // ---- MFMA: wave w computes output cols [w*16, w*16+16) for 16 nodes ----
    const int lr = j & 15;             // within-tile col
    const int lg = j >> 4;             // reg group
    const short8 a0 = *(const short8*)&ts[lr][lg * 8];
    const short8 a1 = *(const short8*)&ts[lr][32 + lg * 8];
    if (FINAL) __syncthreads();        // all A-frags read before ts is reused

    const short8* WpV = (const short8*)WpL;
    f32x4 zac = {0,0,0,0};
    zac = __builtin_amdgcn_mfma_f32_16x16x32_bf16(a0, WpV[(w*2+0)*64 + j], zac, 0, 0, 0);
    zac = __builtin_amdgcn_mfma_f32_16x16x32_bf16(a1, WpV[(w*2+1)*64 + j], zac, 0, 0, 0);

    const float bb = bvec[w * 16 + lr];
    float t0v = 0, t1v = 0, t2v = 0, t3v = 0;
    if (FINAL) { t0v = temp[0]; t1v = temp[1]; t2v = temp[2]; t3v = temp[3]; }
    #pragma unroll
    for (int r = 0; r < 4; ++r) {
        const int row = lg * 4 + r;    // local node
        const int n   = nb + row;
        const float z = zac[r] + swv[row] * bb;
        const float rv = fmaxf(z, 0.0f);
        const size_t o = (size_t)n * HH + w * 16 + lr;
        if (!FINAL) {
            cur_out[o] = f2bf(rv);
        } else {
            const float hid = t0v * bf2f(hbf[o]) + t1v * bf2f(c1[o])
                            + t2v * bf2f(cur_in[o]) + t3v * rv;
            ts[row][w * 16 + lr] = f2bf(hid);
        }
    }
    if (FINAL) {
        __syncthreads();
        const short8 b0 = *(const short8*)&ts[lr][lg * 8];
        const short8 b1 = *(const short8*)&ts[lr][32 + lg * 8];
        const short8* WoV = (const short8*)WpO;
        f32x4 oz = {0,0,0,0};
        oz = __builtin_amdgcn_mfma_f32_16x16x32_bf16(b0, WoV[(w*2+0)*64 + j], oz, 0, 0, 0);
        oz = __builtin_amdgcn_mfma_f32_16x16x32_bf16(b1, WoV[(w*2+1)*64 + j], oz, 0, 0, 0);
        const float bo = bout[w * 16 + lr];
        #pragma unroll
        for (int r = 0; r < 4; ++r) {
            const int row = lg * 4 + r;
            outp[(size_t)(nb + row) * HH + w * 16 + lr] = oz[r] + bo;
        }
    }
}

extern "C" void kernel_launch(void* const* d_in, const int* in_sizes, int n_in,
                              void* d_out, int out_size, void* d_ws, size_t ws_size,
                              hipStream_t stream)
{
    const float* x     = (const float*)d_in[0];
    const int*   ei    = (const int*)d_in[1];
    const float* ew    = (const float*)d_in[2];
    const float* W_in  = (const float*)d_in[3];
    const float* b_in  = (const float*)d_in[4];
    const float* LW    = (const float*)d_in[5];
    const float* Lb    = (const float*)d_in[6];
    const float* W_out = (const float*)d_in[7];
    const float* b_out = (const float*)d_in[8];
    const float* temp  = (const float*)d_in[9];
    const int* src = ei;
    const int* dst = ei + NE;

    char* p = (char*)d_ws;
    ushort* h_bf    = (ushort*)p;  p += (size_t)NN * HH * 2;      // 6.4 MB
    ushort* curA    = (ushort*)p;  p += (size_t)NN * HH * 2;
    ushort* curB    = (ushort*)p;  p += (size_t)NN * HH * 2;
    int2*   epack   = (int2*)p;    p += (size_t)NE * 8;           // 6.4 MB
    int2*   tmp_e   = (int2*)p;    p += (size_t)NE * 8;           // 6.4 MB
    ushort* tmp_low = (ushort*)p;  p += (size_t)NE * 2;           // 1.6 MB
    int*    H       = (int*)p;     p += (size_t)NBINS * B1 * 4;   // 200 KB
    int*    Sx      = (int*)p;     p += (NBINS + 1) * 4;
    int*    bcnt    = (int*)p;     p += NBINS * 4;
    int*    rowptr  = (int*)p;     p += (size_t)NN * 4;
    int*    cnt     = (int*)p;     p += (size_t)NN * 4;
    ushort* Wp      = (ushort*)p;  p += 32768 * 2;                // 64 KB
    float*  out     = (float*)d_out;

    const ushort* WpIn  = Wp;
    const ushort* WpL0  = Wp + 16384;
    const ushort* WpL1  = Wp + 16384 + 4096;
    const ushort* WpL2  = Wp + 16384 + 2 * 4096;
    const ushort* WpOut = Wp + 16384 + 3 * 4096;

    // weights -> bf16 MFMA fragments
    k_prep<<<128, 256, 0, stream>>>(W_in, LW, W_out, Wp);
    // pass-A histogram (LDS only) fused with MFMA in-linear
    k_fused<<<B1 + NGB, 256, 0, stream>>>(x, WpIn, b_in, dst, H, h_bf);
    // global (bin,blk) offsets + bucket bases
    k_scanH<<<1, 256, 0, stream>>>(H, Sx, bcnt);
    // bucket placement (LDS cursors)
    k_scatterA<<<B1, 256, 0, stream>>>(src, dst, ew, H, tmp_e, tmp_low);
    // per-bucket LSD sort -> epack, rowptr, cnt
    k_sortB<<<NBINS, 512, 0, stream>>>(tmp_e, tmp_low, Sx, bcnt, epack, rowptr, cnt);

    // 3 fused propagation layers; FINAL recomputes hidden from bf16 terms
    k_layer<false><<<NLB, 256, 0, stream>>>(h_bf, curA, epack, rowptr, cnt,
                                            WpL0, Lb + 0 * HH, temp,
                                            nullptr, nullptr, nullptr, nullptr, nullptr);
    k_layer<false><<<NLB, 256, 0, stream>>>(curA, curB, epack, rowptr, cnt,
                                            WpL1, Lb + 1 * HH, temp,
                                            nullptr, nullptr, nullptr, nullptr, nullptr);
    k_layer<true><<<NLB, 256, 0, stream>>>(curB, nullptr, epack, rowptr, cnt,
                                           WpL2, Lb + 2 * HH, temp,
                                           h_bf, curA, WpOut, b_out, out);
}

// Round 11
// 135.183 us; speedup vs baseline: 8.9474x; 1.1759x over previous
//
#include <hip/hip_runtime.h>
#include <hip/hip_bf16.h>

#define NN 50000
#define NE 800000
#define CIN 256
#define HH 64
#define NBINS 196         // dst>>8 buckets (50000/256)
#define B1 256            // pass-A blocks
#define EPB 3125          // edges per pass-A block (B1*EPB == NE)
#define NGB 782           // ceil(NN/64) GEMM blocks (64 rows each)
#define NLB 3125          // NN/16 layer blocks (16 nodes each)

typedef unsigned long long u64;
typedef __attribute__((ext_vector_type(8))) short short8;
typedef __attribute__((ext_vector_type(4))) float f32x4;

__device__ __forceinline__ float bf2f(ushort u) {
    union { unsigned int i; float f; } v; v.i = ((unsigned int)u) << 16; return v.f;
}
__device__ __forceinline__ ushort f2bf(float f) {
    __hip_bfloat16 b = __float2bfloat16(f);   // RNE
    return *reinterpret_cast<ushort*>(&b);
}

// ---------------- prep: all weights -> bf16 MFMA B-frag layout ---------------
__global__ __launch_bounds__(256) void k_prep(
    const float* __restrict__ W_in, const float* __restrict__ LW,
    const float* __restrict__ W_out, ushort* __restrict__ Wp)
{
    const int tid = blockIdx.x * 256 + threadIdx.x;   // 32768 total
    if (tid < 16384) {
        const int i = tid & 7;
        const int l = (tid >> 3) & 63;
        const int s = (tid >> 9) & 7;
        const int t = tid >> 12;
        const int k = s * 32 + (l >> 4) * 8 + i;
        const int c = t * 16 + (l & 15);
        Wp[tid] = f2bf(W_in[k * HH + c]);
    } else {
        const int q = (tid - 16384) & 4095;
        const int m = (tid - 16384) >> 12;            // 0..3
        const int i = q & 7;
        const int l = (q >> 3) & 63;
        const int s = (q >> 9) & 1;
        const int t = q >> 10;
        const int k = s * 32 + (l >> 4) * 8 + i;
        const int c = t * 16 + (l & 15);
        const float* Wm = (m < 3) ? (LW + m * HH * HH) : W_out;
        Wp[tid] = f2bf(Wm[k * HH + c]);
    }
}

// ------- fused: pass-A LDS histogram (blocks < B1) | MFMA in-linear ----------
__global__ __launch_bounds__(256) void k_fused(
    const float* __restrict__ x, const ushort* __restrict__ Wp,
    const float* __restrict__ b, const int* __restrict__ dst,
    int* __restrict__ H, ushort* __restrict__ h_bf)
{
    __shared__ int hist[NBINS];
    if (blockIdx.x < B1) {
        for (int t = threadIdx.x; t < NBINS; t += 256) hist[t] = 0;
        __syncthreads();
        const int e0 = blockIdx.x * EPB;
        for (int i = threadIdx.x; i < EPB; i += 256)
            atomicAdd(&hist[dst[e0 + i] >> 8], 1);
        __syncthreads();
        for (int t = threadIdx.x; t < NBINS; t += 256)
            H[t * B1 + blockIdx.x] = hist[t];
        return;
    }
    const int w = threadIdx.x >> 6;          // wave 0..3
    const int l = threadIdx.x & 63;
    const int R0 = (blockIdx.x - B1) * 64 + w * 16;
    const int arow = R0 + (l & 15);
    const int xrow = (arow < NN) ? arow : (NN - 1);
    const float* xr = x + (size_t)xrow * CIN + (l >> 4) * 8;
    const short8* WpV = (const short8*)Wp;

    f32x4 acc0 = {0,0,0,0}, acc1 = {0,0,0,0}, acc2 = {0,0,0,0}, acc3 = {0,0,0,0};
    #pragma unroll
    for (int s = 0; s < 8; ++s) {
        const float4 xa = *(const float4*)(xr + s * 32);
        const float4 xb = *(const float4*)(xr + s * 32 + 4);
        short8 af;
        af[0] = (short)f2bf(xa.x); af[1] = (short)f2bf(xa.y);
        af[2] = (short)f2bf(xa.z); af[3] = (short)f2bf(xa.w);
        af[4] = (short)f2bf(xb.x); af[5] = (short)f2bf(xb.y);
        af[6] = (short)f2bf(xb.z); af[7] = (short)f2bf(xb.w);
        acc0 = __builtin_amdgcn_mfma_f32_16x16x32_bf16(af, WpV[(0*8+s)*64 + l], acc0, 0, 0, 0);
        acc1 = __builtin_amdgcn_mfma_f32_16x16x32_bf16(af, WpV[(1*8+s)*64 + l], acc1, 0, 0, 0);
        acc2 = __builtin_amdgcn_mfma_f32_16x16x32_bf16(af, WpV[(2*8+s)*64 + l], acc2, 0, 0, 0);
        acc3 = __builtin_amdgcn_mfma_f32_16x16x32_bf16(af, WpV[(3*8+s)*64 + l], acc3, 0, 0, 0);
    }
    const int colb = l & 15;
    const int rbase = R0 + (l >> 4) * 4;
    #pragma unroll
    for (int t = 0; t < 4; ++t) {
        const f32x4 a = (t == 0) ? acc0 : (t == 1) ? acc1 : (t == 2) ? acc2 : acc3;
        const float bb = b[t * 16 + colb];
        #pragma unroll
        for (int r = 0; r < 4; ++r) {
            const int row = rbase + r;
            if (row < NN)
                h_bf[(size_t)row * HH + t * 16 + colb] = f2bf(a[r] + bb);
        }
    }
}

// ------- scanS: bin sums + exclusive scan -> Sx, bcnt (1 block) --------------
__global__ __launch_bounds__(256) void k_scanS(
    const int* __restrict__ H, int* __restrict__ Sx, int* __restrict__ bcnt)
{
    __shared__ int s[256];
    const int t = threadIdx.x;
    int rowsum = 0;
    if (t < NBINS) {
        const int4* row = (const int4*)(H + t * B1);
        #pragma unroll 8
        for (int c = 0; c < B1 / 4; ++c) {
            const int4 v = row[c];
            rowsum += v.x + v.y + v.z + v.w;
        }
    }
    s[t] = (t < NBINS) ? rowsum : 0;
    __syncthreads();
    #pragma unroll
    for (int off = 1; off < 256; off <<= 1) {
        const int add = (t >= off) ? s[t - off] : 0;
        __syncthreads();
        s[t] += add;
        __syncthreads();
    }
    if (t < NBINS) {
        Sx[t] = s[t] - rowsum;
        bcnt[t] = rowsum;
    }
}

// ------- scanW: per-bin parallel prefix of per-block counts (in place) -------
__global__ __launch_bounds__(256) void k_scanW(
    int* __restrict__ H, const int* __restrict__ Sx)
{
    __shared__ int s[256];
    const int b = blockIdx.x;          // bin
    const int t = threadIdx.x;         // pass-A block index
    const int v = H[b * B1 + t];
    s[t] = v;
    __syncthreads();
    #pragma unroll
    for (int off = 1; off < 256; off <<= 1) {
        const int add = (t >= off) ? s[t - off] : 0;
        __syncthreads();
        s[t] += add;
        __syncthreads();
    }
    H[b * B1 + t] = s[t] - v + Sx[b];  // global exclusive offset
}

// ------- scatterA: place edges into dst-high buckets (LDS cursors only) ------
__global__ __launch_bounds__(256) void k_scatterA(
    const int* __restrict__ src, const int* __restrict__ dst,
    const float* __restrict__ ew, const int* __restrict__ H,
    int2* __restrict__ tmp_e, ushort* __restrict__ tmp_low)
{
    __shared__ int cur[NBINS];
    for (int t = threadIdx.x; t < NBINS; t += 256)
        cur[t] = H[t * B1 + blockIdx.x];
    __syncthreads();
    const int e0 = blockIdx.x * EPB;
    for (int i = threadIdx.x; i < EPB; i += 256) {
        const int e = e0 + i;
        const int d = dst[e];
        const int pos = atomicAdd(&cur[d >> 8], 1);
        tmp_e[pos] = make_int2(src[e], __float_as_int(ew[e]));
        tmp_low[pos] = (ushort)(d & 255);
    }
}

// ------- sortB: per high-bucket LSD pass -> epack, rowptr, cnt ---------------
__global__ __launch_bounds__(512) void k_sortB(
    const int2* __restrict__ tmp_e, const ushort* __restrict__ tmp_low,
    const int* __restrict__ Sx, const int* __restrict__ bcnt,
    int2* __restrict__ epack, int* __restrict__ rowptr, int* __restrict__ cnt)
{
    __shared__ int hist[256], s[256], curs[256];
    const int b = blockIdx.x;
    const int base = Sx[b];
    const int cntE = bcnt[b];
    const int t = threadIdx.x;
    if (t < 256) hist[t] = 0;
    __syncthreads();
    for (int i = t; i < cntE; i += 512)
        atomicAdd(&hist[tmp_low[base + i]], 1);
    __syncthreads();
    if (t < 256) s[t] = hist[t];
    __syncthreads();
    #pragma unroll
    for (int off = 1; off < 256; off <<= 1) {
        const int add = (t < 256 && t >= off) ? s[t - off] : 0;
        __syncthreads();
        if (t < 256) s[t] += add;
        __syncthreads();
    }
    if (t < 256) {
        const int excl = s[t] - hist[t];
        curs[t] = excl;
        const int d = b * 256 + t;
        if (d < NN) { rowptr[d] = base + excl; cnt[d] = hist[t]; }
    }
    __syncthreads();
    for (int i = t; i < cntE; i += 512) {
        const int2 e = tmp_e[base + i];
        const int low = (int)tmp_low[base + i];
        const int pos = base + atomicAdd(&curs[low], 1);
        epack[pos] = e;
    }
}

// ---------------- fused layer: block = 16 nodes, 4 waves ---------------------
// Per wave: 4 nodes sequential, with the NEXT node's edge-metadata chunk
// prefetched to registers while the current node's gathers are in flight
// (kills the per-node epack-latency stall). es is wave-private: no barriers.
template<bool FINAL>
__global__ __launch_bounds__(256) void k_layer(
    const ushort* __restrict__ cur_in, ushort* __restrict__ cur_out,
    const int2* __restrict__ epack, const int* __restrict__ rowptr,
    const int* __restrict__ cnt,
    const ushort* __restrict__ WpL, const float* __restrict__ bvec,
    const float* __restrict__ temp,
    const ushort* __restrict__ hbf, const ushort* __restrict__ c1,
    const ushort* __restrict__ WpO, const float* __restrict__ bout,
    float* __restrict__ outp)
{
    __shared__ int2  es[4][64];
    __shared__ ushort ts[16][72];      // padded: bank-even b128 reads
    __shared__ float swv[16];          // per-node sum of edge weights (bias term)
    const int w = threadIdx.x >> 6;
    const int j = threadIdx.x & 63;
    const int nb = blockIdx.x * 16;

    int rsA[4], rcA[4];
    #pragma unroll
    for (int q = 0; q < 4; ++q) {
        rsA[q] = rowptr[nb + w * 4 + q];
        rcA[q] = cnt[nb + w * 4 + q];
    }
    // prefetch node 0's first chunk (clamped in-bounds for inactive lanes)
    int2 pf = epack[min(rsA[0] + ((j < rcA[0]) ? j : 0), NE - 1)];

    #pragma unroll
    for (int q = 0; q < 4; ++q) {
        const int rs = rsA[q];
        const int rc = rcA[q];
        es[w][j] = pf;                                 // stage current chunk
        if (q < 3)                                     // issue NEXT chunk now
            pf = epack[min(rsA[q+1] + ((j < rcA[q+1]) ? j : 0), NE - 1)];

        float acc = 0.0f;
        float sw  = 0.0f;
        const int m0 = min(rc, 64);
        for (int g = 0; g < m0; g += 8) {
            float vv[8], ww[8];
            #pragma unroll
            for (int u = 0; u < 8; ++u) {
                const int idx = g + u;
                const int sel = (idx < m0) ? idx : 0;  // clamp: dup line, cheap
                const int2 p = es[w][sel];             // LDS broadcast read
                ww[u] = (idx < m0) ? __int_as_float(p.y) : 0.0f;
                vv[u] = bf2f(cur_in[(size_t)p.x * HH + j]);
            }
            #pragma unroll
            for (int u = 0; u < 8; ++u) { acc = fmaf(ww[u], vv[u], acc); sw += ww[u]; }
        }
        // rare long-tail chunks (deg > 64)
        for (int base = 64; base < rc; base += 64) {
            const int m = min(rc - base, 64);
            if (j < m) es[w][j] = epack[rs + base + j];
            for (int g = 0; g < m; g += 8) {
                float vv[8], ww[8];
                #pragma unroll
                for (int u = 0; u < 8; ++u) {
                    const int idx = g + u;
                    const int sel = (idx < m) ? idx : 0;
                    const int2 p = es[w][sel];
                    ww[u] = (idx < m) ? __int_as_float(p.y) : 0.0f;
                    vv[u] = bf2f(cur_in[(size_t)p.x * HH + j]);
                }
                #pragma unroll
                for (int u = 0; u < 8; ++u) { acc = fmaf(ww[u], vv[u], acc); sw += ww[u]; }
            }
        }
        ts[w * 4 + q][j] = f2bf(acc);
        if (j == 0) swv[w * 4 + q] = sw;
    }
    __syncthreads();

    // ---- MFMA: wave w computes output cols [w*16, w*16+16) for 16 nodes ----
    const int lr = j & 15;             // within-tile col
    const int lg = j >> 4;             // reg group
    const short8 a0 = *(const short8*)&ts[lr][lg * 8];
    const short8 a1 = *(const short8*)&ts[lr][32 + lg * 8];
    if (FINAL) __syncthreads();        // all A-frags read before ts is reused

    const short8* WpV = (const short8*)WpL;
    f32x4 zac = {0,0,0,0};
    zac = __builtin_amdgcn_mfma_f32_16x16x32_bf16(a0, WpV[(w*2+0)*64 + j], zac, 0, 0, 0);
    zac = __builtin_amdgcn_mfma_f32_16x16x32_bf16(a1, WpV[(w*2+1)*64 + j], zac, 0, 0, 0);

    const float bb = bvec[w * 16 + lr];
    float t0v = 0, t1v = 0, t2v = 0, t3v = 0;
    if (FINAL) { t0v = temp[0]; t1v = temp[1]; t2v = temp[2]; t3v = temp[3]; }
    #pragma unroll
    for (int r = 0; r < 4; ++r) {
        const int row = lg * 4 + r;    // local node
        const int n   = nb + row;
        const float z = zac[r] + swv[row] * bb;
        const float rv = fmaxf(z, 0.0f);
        const size_t o = (size_t)n * HH + w * 16 + lr;
        if (!FINAL) {
            cur_out[o] = f2bf(rv);
        } else {
            const float hid = t0v * bf2f(hbf[o]) + t1v * bf2f(c1[o])
                            + t2v * bf2f(cur_in[o]) + t3v * rv;
            ts[row][w * 16 + lr] = f2bf(hid);
        }
    }
    if (FINAL) {
        __syncthreads();
        const short8 b0 = *(const short8*)&ts[lr][lg * 8];
        const short8 b1 = *(const short8*)&ts[lr][32 + lg * 8];
        const short8* WoV = (const short8*)WpO;
        f32x4 oz = {0,0,0,0};
        oz = __builtin_amdgcn_mfma_f32_16x16x32_bf16(b0, WoV[(w*2+0)*64 + j], oz, 0, 0, 0);
        oz = __builtin_amdgcn_mfma_f32_16x16x32_bf16(b1, WoV[(w*2+1)*64 + j], oz, 0, 0, 0);
        const float bo = bout[w * 16 + lr];
        #pragma unroll
        for (int r = 0; r < 4; ++r) {
            const int row = lg * 4 + r;
            outp[(size_t)(nb + row) * HH + w * 16 + lr] = oz[r] + bo;
        }
    }
}

extern "C" void kernel_launch(void* const* d_in, const int* in_sizes, int n_in,
                              void* d_out, int out_size, void* d_ws, size_t ws_size,
                              hipStream_t stream)
{
    const float* x     = (const float*)d_in[0];
    const int*   ei    = (const int*)d_in[1];
    const float* ew    = (const float*)d_in[2];
    const float* W_in  = (const float*)d_in[3];
    const float* b_in  = (const float*)d_in[4];
    const float* LW    = (const float*)d_in[5];
    const float* Lb    = (const float*)d_in[6];
    const float* W_out = (const float*)d_in[7];
    const float* b_out = (const float*)d_in[8];
    const float* temp  = (const float*)d_in[9];
    const int* src = ei;
    const int* dst = ei + NE;

    char* p = (char*)d_ws;
    ushort* h_bf    = (ushort*)p;  p += (size_t)NN * HH * 2;      // 6.4 MB
    ushort* curA    = (ushort*)p;  p += (size_t)NN * HH * 2;
    ushort* curB    = (ushort*)p;  p += (size_t)NN * HH * 2;
    int2*   epack   = (int2*)p;    p += (size_t)NE * 8;           // 6.4 MB
    int2*   tmp_e   = (int2*)p;    p += (size_t)NE * 8;           // 6.4 MB
    ushort* tmp_low = (ushort*)p;  p += (size_t)NE * 2;           // 1.6 MB
    int*    H       = (int*)p;     p += (size_t)NBINS * B1 * 4;   // 200 KB
    int*    Sx      = (int*)p;     p += (NBINS + 1) * 4;
    int*    bcnt    = (int*)p;     p += NBINS * 4;
    int*    rowptr  = (int*)p;     p += (size_t)NN * 4;
    int*    cnt     = (int*)p;     p += (size_t)NN * 4;
    ushort* Wp      = (ushort*)p;  p += 32768 * 2;                // 64 KB
    float*  out     = (float*)d_out;

    const ushort* WpIn  = Wp;
    const ushort* WpL0  = Wp + 16384;
    const ushort* WpL1  = Wp + 16384 + 4096;
    const ushort* WpL2  = Wp + 16384 + 2 * 4096;
    const ushort* WpOut = Wp + 16384 + 3 * 4096;

    // weights -> bf16 MFMA fragments
    k_prep<<<128, 256, 0, stream>>>(W_in, LW, W_out, Wp);
    // pass-A histogram (LDS only) fused with MFMA in-linear
    k_fused<<<B1 + NGB, 256, 0, stream>>>(x, WpIn, b_in, dst, H, h_bf);
    // bin totals + bases (1 tiny block), then parallel per-bin offset rewrite
    k_scanS<<<1, 256, 0, stream>>>(H, Sx, bcnt);
    k_scanW<<<NBINS, 256, 0, stream>>>(H, Sx);
    // bucket placement (LDS cursors)
    k_scatterA<<<B1, 256, 0, stream>>>(src, dst, ew, H, tmp_e, tmp_low);
    // per-bucket LSD sort -> epack, rowptr, cnt
    k_sortB<<<NBINS, 512, 0, stream>>>(tmp_e, tmp_low, Sx, bcnt, epack, rowptr, cnt);

    // 3 fused propagation layers; FINAL recomputes hidden from bf16 terms
    k_layer<false><<<NLB, 256, 0, stream>>>(h_bf, curA, epack, rowptr, cnt,
                                            WpL0, Lb + 0 * HH, temp,
                                            nullptr, nullptr, nullptr, nullptr, nullptr);
    k_layer<false><<<NLB, 256, 0, stream>>>(curA, curB, epack, rowptr, cnt,
                                            WpL1, Lb + 1 * HH, temp,
                                            nullptr, nullptr, nullptr, nullptr, nullptr);
    k_layer<true><<<NLB, 256, 0, stream>>>(curB, nullptr, epack, rowptr, cnt,
                                           WpL2, Lb + 2 * HH, temp,
                                           h_bf, curA, WpOut, b_out, out);
}

// Round 12
// 134.730 us; speedup vs baseline: 8.9775x; 1.0034x over previous
//
#include <hip/hip_runtime.h>
#include <hip/hip_bf16.h>

#define NN 50000
#define NE 800000
#define CIN 256
#define HH 64
#define NBINS 196         // dst>>8 buckets (50000/256)
#define B1 256            // pass-A blocks
#define EPB 3125          // edges per pass-A block (B1*EPB == NE)
#define NGB 782           // ceil(NN/64) GEMM blocks (64 rows each)
#define NLB 3125          // NN/16 layer blocks (16 nodes each)

typedef unsigned long long u64;
typedef __attribute__((ext_vector_type(8))) short short8;
typedef __attribute__((ext_vector_type(4))) float f32x4;

__device__ __forceinline__ float bf2f(ushort u) {
    union { unsigned int i; float f; } v; v.i = ((unsigned int)u) << 16; return v.f;
}
__device__ __forceinline__ ushort f2bf(float f) {
    __hip_bfloat16 b = __float2bfloat16(f);   // RNE
    return *reinterpret_cast<ushort*>(&b);
}

// ---------------- prep: all weights -> bf16 MFMA B-frag layout ---------------
__global__ __launch_bounds__(256) void k_prep(
    const float* __restrict__ W_in, const float* __restrict__ LW,
    const float* __restrict__ W_out, ushort* __restrict__ Wp)
{
    const int tid = blockIdx.x * 256 + threadIdx.x;   // 32768 total
    if (tid < 16384) {
        const int i = tid & 7;
        const int l = (tid >> 3) & 63;
        const int s = (tid >> 9) & 7;
        const int t = tid >> 12;
        const int k = s * 32 + (l >> 4) * 8 + i;
        const int c = t * 16 + (l & 15);
        Wp[tid] = f2bf(W_in[k * HH + c]);
    } else {
        const int q = (tid - 16384) & 4095;
        const int m = (tid - 16384) >> 12;            // 0..3
        const int i = q & 7;
        const int l = (q >> 3) & 63;
        const int s = (q >> 9) & 1;
        const int t = q >> 10;
        const int k = s * 32 + (l >> 4) * 8 + i;
        const int c = t * 16 + (l & 15);
        const float* Wm = (m < 3) ? (LW + m * HH * HH) : W_out;
        Wp[tid] = f2bf(Wm[k * HH + c]);
    }
}

// ------- fused: pass-A LDS histogram (blocks < B1) | MFMA in-linear ----------
__global__ __launch_bounds__(256) void k_fused(
    const float* __restrict__ x, const ushort* __restrict__ Wp,
    const float* __restrict__ b, const int* __restrict__ dst,
    int* __restrict__ H, ushort* __restrict__ h_bf)
{
    __shared__ int hist[NBINS];
    if (blockIdx.x < B1) {
        for (int t = threadIdx.x; t < NBINS; t += 256) hist[t] = 0;
        __syncthreads();
        const int e0 = blockIdx.x * EPB;
        for (int i = threadIdx.x; i < EPB; i += 256)
            atomicAdd(&hist[dst[e0 + i] >> 8], 1);
        __syncthreads();
        for (int t = threadIdx.x; t < NBINS; t += 256)
            H[t * B1 + blockIdx.x] = hist[t];
        return;
    }
    const int w = threadIdx.x >> 6;          // wave 0..3
    const int l = threadIdx.x & 63;
    const int R0 = (blockIdx.x - B1) * 64 + w * 16;
    const int arow = R0 + (l & 15);
    const int xrow = (arow < NN) ? arow : (NN - 1);
    const float* xr = x + (size_t)xrow * CIN + (l >> 4) * 8;
    const short8* WpV = (const short8*)Wp;

    f32x4 acc0 = {0,0,0,0}, acc1 = {0,0,0,0}, acc2 = {0,0,0,0}, acc3 = {0,0,0,0};
    #pragma unroll
    for (int s = 0; s < 8; ++s) {
        const float4 xa = *(const float4*)(xr + s * 32);
        const float4 xb = *(const float4*)(xr + s * 32 + 4);
        short8 af;
        af[0] = (short)f2bf(xa.x); af[1] = (short)f2bf(xa.y);
        af[2] = (short)f2bf(xa.z); af[3] = (short)f2bf(xa.w);
        af[4] = (short)f2bf(xb.x); af[5] = (short)f2bf(xb.y);
        af[6] = (short)f2bf(xb.z); af[7] = (short)f2bf(xb.w);
        acc0 = __builtin_amdgcn_mfma_f32_16x16x32_bf16(af, WpV[(0*8+s)*64 + l], acc0, 0, 0, 0);
        acc1 = __builtin_amdgcn_mfma_f32_16x16x32_bf16(af, WpV[(1*8+s)*64 + l], acc1, 0, 0, 0);
        acc2 = __builtin_amdgcn_mfma_f32_16x16x32_bf16(af, WpV[(2*8+s)*64 + l], acc2, 0, 0, 0);
        acc3 = __builtin_amdgcn_mfma_f32_16x16x32_bf16(af, WpV[(3*8+s)*64 + l], acc3, 0, 0, 0);
    }
    const int colb = l & 15;
    const int rbase = R0 + (l >> 4) * 4;
    #pragma unroll
    for (int t = 0; t < 4; ++t) {
        const f32x4 a = (t == 0) ? acc0 : (t == 1) ? acc1 : (t == 2) ? acc2 : acc3;
        const float bb = b[t * 16 + colb];
        #pragma unroll
        for (int r = 0; r < 4; ++r) {
            const int row = rbase + r;
            if (row < NN)
                h_bf[(size_t)row * HH + t * 16 + colb] = f2bf(a[r] + bb);
        }
    }
}

// ------- scan: per-bin block computes its global base + scans its row --------
// (merged scanS+scanW: each block redundantly sums all preceding bins from H;
//  H is L2-resident, 196 blocks in parallel)
__global__ __launch_bounds__(256) void k_scan(
    int* __restrict__ H, int* __restrict__ Sx, int* __restrict__ bcnt)
{
    __shared__ int s[256];
    const int b = blockIdx.x;
    const int t = threadIdx.x;
    // 1) base = sum of all bins < b
    int partial = 0;
    for (int idx = t; idx < b * B1; idx += 256) partial += H[idx];
    s[t] = partial;
    __syncthreads();
    #pragma unroll
    for (int off = 128; off > 0; off >>= 1) {
        if (t < off) s[t] += s[t + off];
        __syncthreads();
    }
    const int base = s[0];
    __syncthreads();
    // 2) inclusive scan of own row
    const int v = H[b * B1 + t];
    s[t] = v;
    __syncthreads();
    #pragma unroll
    for (int off = 1; off < 256; off <<= 1) {
        const int add = (t >= off) ? s[t - off] : 0;
        __syncthreads();
        s[t] += add;
        __syncthreads();
    }
    H[b * B1 + t] = s[t] - v + base;       // global exclusive offset
    if (t == 255) { Sx[b] = base; bcnt[b] = s[255]; }
}

// ------- scatterA: place edges into dst-high buckets (LDS cursors only) ------
__global__ __launch_bounds__(256) void k_scatterA(
    const int* __restrict__ src, const int* __restrict__ dst,
    const float* __restrict__ ew, const int* __restrict__ H,
    int2* __restrict__ tmp_e, ushort* __restrict__ tmp_low)
{
    __shared__ int cur[NBINS];
    for (int t = threadIdx.x; t < NBINS; t += 256)
        cur[t] = H[t * B1 + blockIdx.x];
    __syncthreads();
    const int e0 = blockIdx.x * EPB;
    for (int i = threadIdx.x; i < EPB; i += 256) {
        const int e = e0 + i;
        const int d = dst[e];
        const int pos = atomicAdd(&cur[d >> 8], 1);
        tmp_e[pos] = make_int2(src[e], __float_as_int(ew[e]));
        tmp_low[pos] = (ushort)(d & 255);
    }
}

// ------- sortB: per high-bucket LSD pass -> epack, rowptr, cnt ---------------
__global__ __launch_bounds__(512) void k_sortB(
    const int2* __restrict__ tmp_e, const ushort* __restrict__ tmp_low,
    const int* __restrict__ Sx, const int* __restrict__ bcnt,
    int2* __restrict__ epack, int* __restrict__ rowptr, int* __restrict__ cnt)
{
    __shared__ int hist[256], s[256], curs[256];
    const int b = blockIdx.x;
    const int base = Sx[b];
    const int cntE = bcnt[b];
    const int t = threadIdx.x;
    if (t < 256) hist[t] = 0;
    __syncthreads();
    for (int i = t; i < cntE; i += 512)
        atomicAdd(&hist[tmp_low[base + i]], 1);
    __syncthreads();
    if (t < 256) s[t] = hist[t];
    __syncthreads();
    #pragma unroll
    for (int off = 1; off < 256; off <<= 1) {
        const int add = (t < 256 && t >= off) ? s[t - off] : 0;
        __syncthreads();
        if (t < 256) s[t] += add;
        __syncthreads();
    }
    if (t < 256) {
        const int excl = s[t] - hist[t];
        curs[t] = excl;
        const int d = b * 256 + t;
        if (d < NN) { rowptr[d] = base + excl; cnt[d] = hist[t]; }
    }
    __syncthreads();
    for (int i = t; i < cntE; i += 512) {
        const int2 e = tmp_e[base + i];
        const int low = (int)tmp_low[base + i];
        const int pos = base + atomicAdd(&curs[low], 1);
        epack[pos] = e;
    }
}

// ---------------- fused layer: block = 16 nodes, 4 waves ---------------------
// Gather: lane j = channel-quad (j&15) of edge-subset (j>>4); one uint2 (8B)
// load per lane -> ONE wave-instruction gathers 4 edges (512B). After the
// edge loop, 2 shfl_xor rounds combine the 4 subsets. Next node's metadata
// chunk is register-prefetched (es is wave-private: no barriers).
template<bool FINAL>
__global__ __launch_bounds__(256) void k_layer(
    const ushort* __restrict__ cur_in, ushort* __restrict__ cur_out,
    const int2* __restrict__ epack, const int* __restrict__ rowptr,
    const int* __restrict__ cnt,
    const ushort* __restrict__ WpL, const float* __restrict__ bvec,
    const float* __restrict__ temp,
    const ushort* __restrict__ hbf, const ushort* __restrict__ c1,
    const ushort* __restrict__ WpO, const float* __restrict__ bout,
    float* __restrict__ outp)
{
    __shared__ int2  es[4][64];
    __shared__ ushort ts[16][72];      // padded rows (144B): bank-even
    __shared__ float swv[16];          // per-node sum of edge weights (bias term)
    const int w = threadIdx.x >> 6;
    const int j = threadIdx.x & 63;
    const int nb = blockIdx.x * 16;
    const int cg  = j >> 4;            // edge-subset 0..3
    const int ch4 = j & 15;            // channel-quad 0..15

    int rsA[4], rcA[4];
    #pragma unroll
    for (int q = 0; q < 4; ++q) {
        rsA[q] = rowptr[nb + w * 4 + q];
        rcA[q] = cnt[nb + w * 4 + q];
    }
    // prefetch node 0's first chunk (clamped in-bounds for inactive lanes)
    int2 pf = epack[min(rsA[0] + ((j < rcA[0]) ? j : 0), NE - 1)];

    #pragma unroll
    for (int q = 0; q < 4; ++q) {
        const int rs = rsA[q];
        const int rc = rcA[q];
        es[w][j] = pf;                                 // stage current chunk
        if (q < 3)                                     // issue NEXT chunk now
            pf = epack[min(rsA[q+1] + ((j < rcA[q+1]) ? j : 0), NE - 1)];

        float4 acc = {0.0f, 0.0f, 0.0f, 0.0f};
        float  sw  = 0.0f;
        const int m0 = min(rc, 64);
        for (int g = 0; g < m0; g += 16) {
            #pragma unroll
            for (int u = 0; u < 4; ++u) {
                const int idx = g + u * 4 + cg;
                const int sel = (idx < m0) ? idx : 0;  // clamp: dup line, L1 hit
                const int2 p = es[w][sel];             // LDS broadcast read
                const float wgt = (idx < m0) ? __int_as_float(p.y) : 0.0f;
                const uint2 v = *(const uint2*)(cur_in + (size_t)p.x * HH + ch4 * 4);
                acc.x = fmaf(wgt, bf2f((ushort)(v.x & 0xffff)), acc.x);
                acc.y = fmaf(wgt, bf2f((ushort)(v.x >> 16)),    acc.y);
                acc.z = fmaf(wgt, bf2f((ushort)(v.y & 0xffff)), acc.z);
                acc.w = fmaf(wgt, bf2f((ushort)(v.y >> 16)),    acc.w);
                sw += wgt;
            }
        }
        // rare long-tail chunks (deg > 64)
        for (int base = 64; base < rc; base += 64) {
            const int m = min(rc - base, 64);
            if (j < m) es[w][j] = epack[rs + base + j];
            for (int g = 0; g < m; g += 16) {
                #pragma unroll
                for (int u = 0; u < 4; ++u) {
                    const int idx = g + u * 4 + cg;
                    const int sel = (idx < m) ? idx : 0;
                    const int2 p = es[w][sel];
                    const float wgt = (idx < m) ? __int_as_float(p.y) : 0.0f;
                    const uint2 v = *(const uint2*)(cur_in + (size_t)p.x * HH + ch4 * 4);
                    acc.x = fmaf(wgt, bf2f((ushort)(v.x & 0xffff)), acc.x);
                    acc.y = fmaf(wgt, bf2f((ushort)(v.x >> 16)),    acc.y);
                    acc.z = fmaf(wgt, bf2f((ushort)(v.y & 0xffff)), acc.z);
                    acc.w = fmaf(wgt, bf2f((ushort)(v.y >> 16)),    acc.w);
                    sw += wgt;
                }
            }
        }
        // combine the 4 edge-subsets: lanes {j, j^16, j^32, j^48}
        #pragma unroll
        for (int off = 16; off < 64; off <<= 1) {
            acc.x += __shfl_xor(acc.x, off);
            acc.y += __shfl_xor(acc.y, off);
            acc.z += __shfl_xor(acc.z, off);
            acc.w += __shfl_xor(acc.w, off);
            sw    += __shfl_xor(sw, off);
        }
        if (j < 16) {
            const int node = w * 4 + q;
            uint2 o;
            o.x = (uint)f2bf(acc.x) | ((uint)f2bf(acc.y) << 16);
            o.y = (uint)f2bf(acc.z) | ((uint)f2bf(acc.w) << 16);
            *(uint2*)&ts[node][ch4 * 4] = o;           // 16 lanes x 8B: conflict-free
            if (j == 0) swv[node] = sw;
        }
    }
    __syncthreads();

    // ---- MFMA: wave w computes output cols [w*16, w*16+16) for 16 nodes ----
    const int lr = j & 15;             // within-tile col
    const int lg = j >> 4;             // reg group
    const short8 a0 = *(const short8*)&ts[lr][lg * 8];
    const short8 a1 = *(const short8*)&ts[lr][32 + lg * 8];
    if (FINAL) __syncthreads();        // all A-frags read before ts is reused

    const short8* WpV = (const short8*)WpL;
    f32x4 zac = {0,0,0,0};
    zac = __builtin_amdgcn_mfma_f32_16x16x32_bf16(a0, WpV[(w*2+0)*64 + j], zac, 0, 0, 0);
    zac = __builtin_amdgcn_mfma_f32_16x16x32_bf16(a1, WpV[(w*2+1)*64 + j], zac, 0, 0, 0);

    const float bb = bvec[w * 16 + lr];
    float t0v = 0, t1v = 0, t2v = 0, t3v = 0;
    if (FINAL) { t0v = temp[0]; t1v = temp[1]; t2v = temp[2]; t3v = temp[3]; }
    #pragma unroll
    for (int r = 0; r < 4; ++r) {
        const int row = lg * 4 + r;    // local node
        const int n   = nb + row;
        const float z = zac[r] + swv[row] * bb;
        const float rv = fmaxf(z, 0.0f);
        const size_t o = (size_t)n * HH + w * 16 + lr;
        if (!FINAL) {
            cur_out[o] = f2bf(rv);
        } else {
            const float hid = t0v * bf2f(hbf[o]) + t1v * bf2f(c1[o])
                            + t2v * bf2f(cur_in[o]) + t3v * rv;
            ts[row][w * 16 + lr] = f2bf(hid);
        }
    }
    if (FINAL) {
        __syncthreads();
        const short8 b0 = *(const short8*)&ts[lr][lg * 8];
        const short8 b1 = *(const short8*)&ts[lr][32 + lg * 8];
        const short8* WoV = (const short8*)WpO;
        f32x4 oz = {0,0,0,0};
        oz = __builtin_amdgcn_mfma_f32_16x16x32_bf16(b0, WoV[(w*2+0)*64 + j], oz, 0, 0, 0);
        oz = __builtin_amdgcn_mfma_f32_16x16x32_bf16(b1, WoV[(w*2+1)*64 + j], oz, 0, 0, 0);
        const float bo = bout[w * 16 + lr];
        #pragma unroll
        for (int r = 0; r < 4; ++r) {
            const int row = lg * 4 + r;
            outp[(size_t)(nb + row) * HH + w * 16 + lr] = oz[r] + bo;
        }
    }
}

extern "C" void kernel_launch(void* const* d_in, const int* in_sizes, int n_in,
                              void* d_out, int out_size, void* d_ws, size_t ws_size,
                              hipStream_t stream)
{
    const float* x     = (const float*)d_in[0];
    const int*   ei    = (const int*)d_in[1];
    const float* ew    = (const float*)d_in[2];
    const float* W_in  = (const float*)d_in[3];
    const float* b_in  = (const float*)d_in[4];
    const float* LW    = (const float*)d_in[5];
    const float* Lb    = (const float*)d_in[6];
    const float* W_out = (const float*)d_in[7];
    const float* b_out = (const float*)d_in[8];
    const float* temp  = (const float*)d_in[9];
    const int* src = ei;
    const int* dst = ei + NE;

    char* p = (char*)d_ws;
    ushort* h_bf    = (ushort*)p;  p += (size_t)NN * HH * 2;      // 6.4 MB
    ushort* curA    = (ushort*)p;  p += (size_t)NN * HH * 2;
    ushort* curB    = (ushort*)p;  p += (size_t)NN * HH * 2;
    int2*   epack   = (int2*)p;    p += (size_t)NE * 8;           // 6.4 MB
    int2*   tmp_e   = (int2*)p;    p += (size_t)NE * 8;           // 6.4 MB
    ushort* tmp_low = (ushort*)p;  p += (size_t)NE * 2;           // 1.6 MB
    int*    H       = (int*)p;     p += (size_t)NBINS * B1 * 4;   // 200 KB
    int*    Sx      = (int*)p;     p += (NBINS + 1) * 4;
    int*    bcnt    = (int*)p;     p += NBINS * 4;
    int*    rowptr  = (int*)p;     p += (size_t)NN * 4;
    int*    cnt     = (int*)p;     p += (size_t)NN * 4;
    ushort* Wp      = (ushort*)p;  p += 32768 * 2;                // 64 KB
    float*  out     = (float*)d_out;

    const ushort* WpIn  = Wp;
    const ushort* WpL0  = Wp + 16384;
    const ushort* WpL1  = Wp + 16384 + 4096;
    const ushort* WpL2  = Wp + 16384 + 2 * 4096;
    const ushort* WpOut = Wp + 16384 + 3 * 4096;

    // weights -> bf16 MFMA fragments
    k_prep<<<128, 256, 0, stream>>>(W_in, LW, W_out, Wp);
    // pass-A histogram (LDS only) fused with MFMA in-linear
    k_fused<<<B1 + NGB, 256, 0, stream>>>(x, WpIn, b_in, dst, H, h_bf);
    // merged scan: per-bin base + row offsets in one launch
    k_scan<<<NBINS, 256, 0, stream>>>(H, Sx, bcnt);
    // bucket placement (LDS cursors)
    k_scatterA<<<B1, 256, 0, stream>>>(src, dst, ew, H, tmp_e, tmp_low);
    // per-bucket LSD sort -> epack, rowptr, cnt
    k_sortB<<<NBINS, 512, 0, stream>>>(tmp_e, tmp_low, Sx, bcnt, epack, rowptr, cnt);

    // 3 fused propagation layers; FINAL recomputes hidden from bf16 terms
    k_layer<false><<<NLB, 256, 0, stream>>>(h_bf, curA, epack, rowptr, cnt,
                                            WpL0, Lb + 0 * HH, temp,
                                            nullptr, nullptr, nullptr, nullptr, nullptr);
    k_layer<false><<<NLB, 256, 0, stream>>>(curA, curB, epack, rowptr, cnt,
                                            WpL1, Lb + 1 * HH, temp,
                                            nullptr, nullptr, nullptr, nullptr, nullptr);
    k_layer<true><<<NLB, 256, 0, stream>>>(curB, nullptr, epack, rowptr, cnt,
                                           WpL2, Lb + 2 * HH, temp,
                                           h_bf, curA, WpOut, b_out, out);
}

// Round 13
// 127.358 us; speedup vs baseline: 9.4972x; 1.0579x over previous
//
#include <hip/hip_runtime.h>
#include <hip/hip_bf16.h>

#define NN 50000
#define NE 800000
#define CIN 256
#define HH 64
#define NBINS 196         // dst>>8 buckets (50000/256)
#define B1 256            // pass-A blocks
#define EPB 3125          // edges per pass-A block (B1*EPB == NE)
#define NGB 782           // ceil(NN/64) GEMM blocks (64 rows each)
#define NLB 3125          // NN/16 layer blocks (16 nodes each)

typedef unsigned long long u64;
typedef __attribute__((ext_vector_type(8))) short short8;
typedef __attribute__((ext_vector_type(4))) float f32x4;

__device__ __forceinline__ float bf2f(ushort u) {
    union { unsigned int i; float f; } v; v.i = ((unsigned int)u) << 16; return v.f;
}
__device__ __forceinline__ ushort f2bf(float f) {
    __hip_bfloat16 b = __float2bfloat16(f);   // RNE
    return *reinterpret_cast<ushort*>(&b);
}

// ------- prep (blocks >= B1): weights -> bf16 MFMA B-frag layout -------------
// ------- hist (blocks <  B1): per-block LDS histogram of dst>>8 --------------
__global__ __launch_bounds__(256) void k_prep_hist(
    const float* __restrict__ W_in, const float* __restrict__ LW,
    const float* __restrict__ W_out, ushort* __restrict__ Wp,
    const int* __restrict__ dst, int* __restrict__ H)
{
    __shared__ int hist[NBINS];
    if (blockIdx.x < B1) {
        for (int t = threadIdx.x; t < NBINS; t += 256) hist[t] = 0;
        __syncthreads();
        const int e0 = blockIdx.x * EPB;
        for (int i = threadIdx.x; i < EPB; i += 256)
            atomicAdd(&hist[dst[e0 + i] >> 8], 1);
        __syncthreads();
        for (int t = threadIdx.x; t < NBINS; t += 256)
            H[t * B1 + blockIdx.x] = hist[t];
        return;
    }
    const int tid = (blockIdx.x - B1) * 256 + threadIdx.x;   // 32768 total
    if (tid < 16384) {
        const int i = tid & 7;
        const int l = (tid >> 3) & 63;
        const int s = (tid >> 9) & 7;
        const int t = tid >> 12;
        const int k = s * 32 + (l >> 4) * 8 + i;
        const int c = t * 16 + (l & 15);
        Wp[tid] = f2bf(W_in[k * HH + c]);
    } else {
        const int q = (tid - 16384) & 4095;
        const int m = (tid - 16384) >> 12;            // 0..3
        const int i = q & 7;
        const int l = (q >> 3) & 63;
        const int s = (q >> 9) & 1;
        const int t = q >> 10;
        const int k = s * 32 + (l >> 4) * 8 + i;
        const int c = t * 16 + (l & 15);
        const float* Wm = (m < 3) ? (LW + m * HH * HH) : W_out;
        Wp[tid] = f2bf(Wm[k * HH + c]);
    }
}

// ------- scan: per-bin block computes its global base + scans its row --------
__global__ __launch_bounds__(256) void k_scan(
    int* __restrict__ H, int* __restrict__ Sx, int* __restrict__ bcnt)
{
    __shared__ int s[256];
    const int b = blockIdx.x;
    const int t = threadIdx.x;
    int partial = 0;
    for (int idx = t; idx < b * B1; idx += 256) partial += H[idx];
    s[t] = partial;
    __syncthreads();
    #pragma unroll
    for (int off = 128; off > 0; off >>= 1) {
        if (t < off) s[t] += s[t + off];
        __syncthreads();
    }
    const int base = s[0];
    __syncthreads();
    const int v = H[b * B1 + t];
    s[t] = v;
    __syncthreads();
    #pragma unroll
    for (int off = 1; off < 256; off <<= 1) {
        const int add = (t >= off) ? s[t - off] : 0;
        __syncthreads();
        s[t] += add;
        __syncthreads();
    }
    H[b * B1 + t] = s[t] - v + base;       // global exclusive offset
    if (t == 255) { Sx[b] = base; bcnt[b] = s[255]; }
}

// ------- fused2: scatterA (blocks < B1) | MFMA in-linear (rest) --------------
// scatter: place edges into dst-high buckets (LDS cursors); dlow packed into
// tmp_e.x bits 16..23 (src < 2^16).
// GEMM: h = x @ W_in + b_in -> bf16; ALL 16 x-float4 preloaded before MFMAs.
__global__ __launch_bounds__(256) void k_fused2(
    const float* __restrict__ x, const ushort* __restrict__ Wp,
    const float* __restrict__ b,
    const int* __restrict__ src, const int* __restrict__ dst,
    const float* __restrict__ ew, const int* __restrict__ H,
    int2* __restrict__ tmp_e, ushort* __restrict__ h_bf)
{
    __shared__ int cur[NBINS];
    if (blockIdx.x < B1) {
        for (int t = threadIdx.x; t < NBINS; t += 256)
            cur[t] = H[t * B1 + blockIdx.x];
        __syncthreads();
        const int e0 = blockIdx.x * EPB;
        for (int i = threadIdx.x; i < EPB; i += 256) {
            const int e = e0 + i;
            const int d = dst[e];
            const int pos = atomicAdd(&cur[d >> 8], 1);
            tmp_e[pos] = make_int2(src[e] | ((d & 255) << 16), __float_as_int(ew[e]));
        }
        return;
    }
    const int w = threadIdx.x >> 6;          // wave 0..3
    const int l = threadIdx.x & 63;
    const int R0 = (blockIdx.x - B1) * 64 + w * 16;
    const int arow = R0 + (l & 15);
    const int xrow = (arow < NN) ? arow : (NN - 1);
    const float* xr = x + (size_t)xrow * CIN + (l >> 4) * 8;

    // preload the whole K-slice of this lane's x row (16 float4 in flight)
    float4 xv[16];
    #pragma unroll
    for (int s = 0; s < 8; ++s) {
        xv[2*s]   = *(const float4*)(xr + s * 32);
        xv[2*s+1] = *(const float4*)(xr + s * 32 + 4);
    }

    const short8* WpV = (const short8*)Wp;
    f32x4 acc0 = {0,0,0,0}, acc1 = {0,0,0,0}, acc2 = {0,0,0,0}, acc3 = {0,0,0,0};
    #pragma unroll
    for (int s = 0; s < 8; ++s) {
        const float4 xa = xv[2*s];
        const float4 xb = xv[2*s+1];
        short8 af;
        af[0] = (short)f2bf(xa.x); af[1] = (short)f2bf(xa.y);
        af[2] = (short)f2bf(xa.z); af[3] = (short)f2bf(xa.w);
        af[4] = (short)f2bf(xb.x); af[5] = (short)f2bf(xb.y);
        af[6] = (short)f2bf(xb.z); af[7] = (short)f2bf(xb.w);
        acc0 = __builtin_amdgcn_mfma_f32_16x16x32_bf16(af, WpV[(0*8+s)*64 + l], acc0, 0, 0, 0);
        acc1 = __builtin_amdgcn_mfma_f32_16x16x32_bf16(af, WpV[(1*8+s)*64 + l], acc1, 0, 0, 0);
        acc2 = __builtin_amdgcn_mfma_f32_16x16x32_bf16(af, WpV[(2*8+s)*64 + l], acc2, 0, 0, 0);
        acc3 = __builtin_amdgcn_mfma_f32_16x16x32_bf16(af, WpV[(3*8+s)*64 + l], acc3, 0, 0, 0);
    }
    const int colb = l & 15;
    const int rbase = R0 + (l >> 4) * 4;
    #pragma unroll
    for (int t = 0; t < 4; ++t) {
        const f32x4 a = (t == 0) ? acc0 : (t == 1) ? acc1 : (t == 2) ? acc2 : acc3;
        const float bb = b[t * 16 + colb];
        #pragma unroll
        for (int r = 0; r < 4; ++r) {
            const int row = rbase + r;
            if (row < NN)
                h_bf[(size_t)row * HH + t * 16 + colb] = f2bf(a[r] + bb);
        }
    }
}

// ------- sortB: per high-bucket LSD pass -> epack, rowptr, cnt ---------------
__global__ __launch_bounds__(512) void k_sortB(
    const int2* __restrict__ tmp_e,
    const int* __restrict__ Sx, const int* __restrict__ bcnt,
    int2* __restrict__ epack, int* __restrict__ rowptr, int* __restrict__ cnt)
{
    __shared__ int hist[256], s[256], curs[256];
    const int b = blockIdx.x;
    const int base = Sx[b];
    const int cntE = bcnt[b];
    const int t = threadIdx.x;
    if (t < 256) hist[t] = 0;
    __syncthreads();
    for (int i = t; i < cntE; i += 512)
        atomicAdd(&hist[(tmp_e[base + i].x >> 16) & 255], 1);
    __syncthreads();
    if (t < 256) s[t] = hist[t];
    __syncthreads();
    #pragma unroll
    for (int off = 1; off < 256; off <<= 1) {
        const int add = (t < 256 && t >= off) ? s[t - off] : 0;
        __syncthreads();
        if (t < 256) s[t] += add;
        __syncthreads();
    }
    if (t < 256) {
        const int excl = s[t] - hist[t];
        curs[t] = excl;
        const int d = b * 256 + t;
        if (d < NN) { rowptr[d] = base + excl; cnt[d] = hist[t]; }
    }
    __syncthreads();
    for (int i = t; i < cntE; i += 512) {
        const int2 e = tmp_e[base + i];
        const int low = (e.x >> 16) & 255;
        const int pos = base + atomicAdd(&curs[low], 1);
        epack[pos] = make_int2(e.x & 0xFFFF, e.y);
    }
}

// ---------------- fused layer: block = 16 nodes, 4 waves ---------------------
// Gather: lane j = channel-quad (j&15) of edge-subset (j>>4); one uint2 (8B)
// load per lane -> one wave-instruction gathers 4 edges. Next node's metadata
// chunk is register-prefetched (es is wave-private: no barriers).
template<bool FINAL>
__global__ __launch_bounds__(256) void k_layer(
    const ushort* __restrict__ cur_in, ushort* __restrict__ cur_out,
    const int2* __restrict__ epack, const int* __restrict__ rowptr,
    const int* __restrict__ cnt,
    const ushort* __restrict__ WpL, const float* __restrict__ bvec,
    const float* __restrict__ temp,
    const ushort* __restrict__ hbf, const ushort* __restrict__ c1,
    const ushort* __restrict__ WpO, const float* __restrict__ bout,
    float* __restrict__ outp)
{
    __shared__ int2  es[4][64];
    __shared__ ushort ts[16][72];      // padded rows (144B): bank-even
    __shared__ float swv[16];          // per-node sum of edge weights (bias term)
    const int w = threadIdx.x >> 6;
    const int j = threadIdx.x & 63;
    const int nb = blockIdx.x * 16;
    const int cg  = j >> 4;            // edge-subset 0..3
    const int ch4 = j & 15;            // channel-quad 0..15

    int rsA[4], rcA[4];
    #pragma unroll
    for (int q = 0; q < 4; ++q) {
        rsA[q] = rowptr[nb + w * 4 + q];
        rcA[q] = cnt[nb + w * 4 + q];
    }
    int2 pf = epack[min(rsA[0] + ((j < rcA[0]) ? j : 0), NE - 1)];

    #pragma unroll
    for (int q = 0; q < 4; ++q) {
        const int rs = rsA[q];
        const int rc = rcA[q];
        es[w][j] = pf;                                 // stage current chunk
        if (q < 3)                                     // issue NEXT chunk now
            pf = epack[min(rsA[q+1] + ((j < rcA[q+1]) ? j : 0), NE - 1)];

        float4 acc = {0.0f, 0.0f, 0.0f, 0.0f};
        float  sw  = 0.0f;
        const int m0 = min(rc, 64);
        for (int g = 0; g < m0; g += 16) {
            #pragma unroll
            for (int u = 0; u < 4; ++u) {
                const int idx = g + u * 4 + cg;
                const int sel = (idx < m0) ? idx : 0;  // clamp: dup line, L1 hit
                const int2 p = es[w][sel];             // LDS broadcast read
                const float wgt = (idx < m0) ? __int_as_float(p.y) : 0.0f;
                const uint2 v = *(const uint2*)(cur_in + (size_t)p.x * HH + ch4 * 4);
                acc.x = fmaf(wgt, bf2f((ushort)(v.x & 0xffff)), acc.x);
                acc.y = fmaf(wgt, bf2f((ushort)(v.x >> 16)),    acc.y);
                acc.z = fmaf(wgt, bf2f((ushort)(v.y & 0xffff)), acc.z);
                acc.w = fmaf(wgt, bf2f((ushort)(v.y >> 16)),    acc.w);
                sw += wgt;
            }
        }
        for (int base = 64; base < rc; base += 64) {   // rare long tails
            const int m = min(rc - base, 64);
            if (j < m) es[w][j] = epack[rs + base + j];
            for (int g = 0; g < m; g += 16) {
                #pragma unroll
                for (int u = 0; u < 4; ++u) {
                    const int idx = g + u * 4 + cg;
                    const int sel = (idx < m) ? idx : 0;
                    const int2 p = es[w][sel];
                    const float wgt = (idx < m) ? __int_as_float(p.y) : 0.0f;
                    const uint2 v = *(const uint2*)(cur_in + (size_t)p.x * HH + ch4 * 4);
                    acc.x = fmaf(wgt, bf2f((ushort)(v.x & 0xffff)), acc.x);
                    acc.y = fmaf(wgt, bf2f((ushort)(v.x >> 16)),    acc.y);
                    acc.z = fmaf(wgt, bf2f((ushort)(v.y & 0xffff)), acc.z);
                    acc.w = fmaf(wgt, bf2f((ushort)(v.y >> 16)),    acc.w);
                    sw += wgt;
                }
            }
        }
        #pragma unroll
        for (int off = 16; off < 64; off <<= 1) {
            acc.x += __shfl_xor(acc.x, off);
            acc.y += __shfl_xor(acc.y, off);
            acc.z += __shfl_xor(acc.z, off);
            acc.w += __shfl_xor(acc.w, off);
            sw    += __shfl_xor(sw, off);
        }
        if (j < 16) {
            const int node = w * 4 + q;
            uint2 o;
            o.x = (uint)f2bf(acc.x) | ((uint)f2bf(acc.y) << 16);
            o.y = (uint)f2bf(acc.z) | ((uint)f2bf(acc.w) << 16);
            *(uint2*)&ts[node][ch4 * 4] = o;           // 16 lanes x 8B: conflict-free
            if (j == 0) swv[node] = sw;
        }
    }
    __syncthreads();

    // ---- MFMA: wave w computes output cols [w*16, w*16+16) for 16 nodes ----
    const int lr = j & 15;
    const int lg = j >> 4;
    const short8 a0 = *(const short8*)&ts[lr][lg * 8];
    const short8 a1 = *(const short8*)&ts[lr][32 + lg * 8];
    if (FINAL) __syncthreads();        // all A-frags read before ts is reused

    const short8* WpV = (const short8*)WpL;
    f32x4 zac = {0,0,0,0};
    zac = __builtin_amdgcn_mfma_f32_16x16x32_bf16(a0, WpV[(w*2+0)*64 + j], zac, 0, 0, 0);
    zac = __builtin_amdgcn_mfma_f32_16x16x32_bf16(a1, WpV[(w*2+1)*64 + j], zac, 0, 0, 0);

    const float bb = bvec[w * 16 + lr];
    float t0v = 0, t1v = 0, t2v = 0, t3v = 0;
    if (FINAL) { t0v = temp[0]; t1v = temp[1]; t2v = temp[2]; t3v = temp[3]; }
    #pragma unroll
    for (int r = 0; r < 4; ++r) {
        const int row = lg * 4 + r;
        const int n   = nb + row;
        const float z = zac[r] + swv[row] * bb;
        const float rv = fmaxf(z, 0.0f);
        const size_t o = (size_t)n * HH + w * 16 + lr;
        if (!FINAL) {
            cur_out[o] = f2bf(rv);
        } else {
            const float hid = t0v * bf2f(hbf[o]) + t1v * bf2f(c1[o])
                            + t2v * bf2f(cur_in[o]) + t3v * rv;
            ts[row][w * 16 + lr] = f2bf(hid);
        }
    }
    if (FINAL) {
        __syncthreads();
        const short8 b0 = *(const short8*)&ts[lr][lg * 8];
        const short8 b1 = *(const short8*)&ts[lr][32 + lg * 8];
        const short8* WoV = (const short8*)WpO;
        f32x4 oz = {0,0,0,0};
        oz = __builtin_amdgcn_mfma_f32_16x16x32_bf16(b0, WoV[(w*2+0)*64 + j], oz, 0, 0, 0);
        oz = __builtin_amdgcn_mfma_f32_16x16x32_bf16(b1, WoV[(w*2+1)*64 + j], oz, 0, 0, 0);
        const float bo = bout[w * 16 + lr];
        #pragma unroll
        for (int r = 0; r < 4; ++r) {
            const int row = lg * 4 + r;
            outp[(size_t)(nb + row) * HH + w * 16 + lr] = oz[r] + bo;
        }
    }
}

extern "C" void kernel_launch(void* const* d_in, const int* in_sizes, int n_in,
                              void* d_out, int out_size, void* d_ws, size_t ws_size,
                              hipStream_t stream)
{
    const float* x     = (const float*)d_in[0];
    const int*   ei    = (const int*)d_in[1];
    const float* ew    = (const float*)d_in[2];
    const float* W_in  = (const float*)d_in[3];
    const float* b_in  = (const float*)d_in[4];
    const float* LW    = (const float*)d_in[5];
    const float* Lb    = (const float*)d_in[6];
    const float* W_out = (const float*)d_in[7];
    const float* b_out = (const float*)d_in[8];
    const float* temp  = (const float*)d_in[9];
    const int* src = ei;
    const int* dst = ei + NE;

    char* p = (char*)d_ws;
    ushort* h_bf    = (ushort*)p;  p += (size_t)NN * HH * 2;      // 6.4 MB
    ushort* curA    = (ushort*)p;  p += (size_t)NN * HH * 2;
    ushort* curB    = (ushort*)p;  p += (size_t)NN * HH * 2;
    int2*   epack   = (int2*)p;    p += (size_t)NE * 8;           // 6.4 MB
    int2*   tmp_e   = (int2*)p;    p += (size_t)NE * 8;           // 6.4 MB
    int*    H       = (int*)p;     p += (size_t)NBINS * B1 * 4;   // 200 KB
    int*    Sx      = (int*)p;     p += (NBINS + 1) * 4;
    int*    bcnt    = (int*)p;     p += NBINS * 4;
    int*    rowptr  = (int*)p;     p += (size_t)NN * 4;
    int*    cnt     = (int*)p;     p += (size_t)NN * 4;
    ushort* Wp      = (ushort*)p;  p += 32768 * 2;                // 64 KB
    float*  out     = (float*)d_out;

    const ushort* WpIn  = Wp;
    const ushort* WpL0  = Wp + 16384;
    const ushort* WpL1  = Wp + 16384 + 4096;
    const ushort* WpL2  = Wp + 16384 + 2 * 4096;
    const ushort* WpOut = Wp + 16384 + 3 * 4096;

    // hist (256 blocks) + weight prep (128 blocks) in one cheap kernel
    k_prep_hist<<<B1 + 128, 256, 0, stream>>>(W_in, LW, W_out, Wp, dst, H);
    // per-bin base + row offsets
    k_scan<<<NBINS, 256, 0, stream>>>(H, Sx, bcnt);
    // scatterA (256 blocks) hidden under the MFMA in-linear (782 blocks)
    k_fused2<<<B1 + NGB, 256, 0, stream>>>(x, WpIn, b_in, src, dst, ew, H,
                                           tmp_e, h_bf);
    // per-bucket LSD sort -> epack, rowptr, cnt
    k_sortB<<<NBINS, 512, 0, stream>>>(tmp_e, Sx, bcnt, epack, rowptr, cnt);

    // 3 fused propagation layers; FINAL recomputes hidden from bf16 terms
    k_layer<false><<<NLB, 256, 0, stream>>>(h_bf, curA, epack, rowptr, cnt,
                                            WpL0, Lb + 0 * HH, temp,
                                            nullptr, nullptr, nullptr, nullptr, nullptr);
    k_layer<false><<<NLB, 256, 0, stream>>>(curA, curB, epack, rowptr, cnt,
                                            WpL1, Lb + 1 * HH, temp,
                                            nullptr, nullptr, nullptr, nullptr, nullptr);
    k_layer<true><<<NLB, 256, 0, stream>>>(curB, nullptr, epack, rowptr, cnt,
                                           WpL2, Lb + 2 * HH, temp,
                                           h_bf, curA, WpOut, b_out, out);
}